// Round 1
// baseline (26974.036 us; speedup 1.0000x reference)
//
#include <hip/hip_runtime.h>
#include <hip/hip_bf16.h>

#define V_ 32000
#define H_ 1024
#define NH_ 16
#define I_ 4096
#define L_ 8
#define B_ 2
#define S_ 2048
#define DH_ 64
#define M_ 4096  // B_*S_

typedef __attribute__((ext_vector_type(4))) float f32x4;
typedef __attribute__((ext_vector_type(8))) short s16x8;

__device__ __forceinline__ unsigned short f2b(float f) {
  union { float f; unsigned u; } x; x.f = f;
  return (unsigned short)((x.u + 0x7FFFu + ((x.u >> 16) & 1u)) >> 16);
}

// ---------------- embedding: h = tok[ids] + pos, also bf16 copy ----------------
__global__ __launch_bounds__(256) void embed_kernel(
    const int* __restrict__ ids, const float* __restrict__ tok,
    const float* __restrict__ pos, float* __restrict__ h,
    unsigned short* __restrict__ xbf)
{
  int row = blockIdx.x;
  int c = blockIdx.y * 256 + threadIdx.x;
  int id = ids[row];
  int s = row & (S_ - 1);
  float v = tok[(size_t)id * H_ + c] + pos[(size_t)s * H_ + c];
  h[(size_t)row * H_ + c] = v;
  xbf[(size_t)row * H_ + c] = f2b(v);
}

// ---------------- GEMM: out[M,N] = A[M,K](bf16) @ W[N,K]^T (f32->bf16) + bias --
// EPI 0: f32 out + bias.  EPI 1: gelu(x+bias) -> bf16 out.
template<int EPI>
__global__ __launch_bounds__(256) void gemm_bt(
    const unsigned short* __restrict__ A, const float* __restrict__ Wt,
    const float* __restrict__ bias, float* __restrict__ outf,
    unsigned short* __restrict__ outb, int M, int N, int K)
{
  __shared__ unsigned short As[128][32];
  __shared__ unsigned short Bs[128][32];
  int t = threadIdx.x;
  int lane = t & 63, wid = t >> 6;
  int m0 = blockIdx.x * 128, n0 = blockIdx.y * 128;
  int wm = (wid >> 1) * 64, wn = (wid & 1) * 64;

  f32x4 acc[4][4] = {};

  int ar = t >> 2, ac = (t & 3) * 8;   // A staging: 2 rounds of 16B/thread
  int wr = t >> 3, wc = (t & 7) * 4;   // W staging: 4 rounds of float4/thread
  int fr = lane & 15, kh = (lane >> 4) * 8;

  for (int k0 = 0; k0 < K; k0 += 32) {
    #pragma unroll
    for (int r = 0; r < 2; ++r) {
      const int4 d = *(const int4*)(A + (size_t)(m0 + r * 64 + ar) * K + k0 + ac);
      *(int4*)(&As[r * 64 + ar][ac]) = d;
    }
    #pragma unroll
    for (int r = 0; r < 4; ++r) {
      const float4 d = *(const float4*)(Wt + (size_t)(n0 + r * 32 + wr) * K + k0 + wc);
      ushort4 b4;
      b4.x = f2b(d.x); b4.y = f2b(d.y); b4.z = f2b(d.z); b4.w = f2b(d.w);
      *(ushort4*)(&Bs[r * 32 + wr][wc]) = b4;
    }
    __syncthreads();
    s16x8 af[4], bfr[4];
    #pragma unroll
    for (int i = 0; i < 4; ++i) af[i]  = *(const s16x8*)(&As[wm + i * 16 + fr][kh]);
    #pragma unroll
    for (int j = 0; j < 4; ++j) bfr[j] = *(const s16x8*)(&Bs[wn + j * 16 + fr][kh]);
    #pragma unroll
    for (int i = 0; i < 4; ++i)
      #pragma unroll
      for (int j = 0; j < 4; ++j)
        acc[i][j] = __builtin_amdgcn_mfma_f32_16x16x32_bf16(af[i], bfr[j], acc[i][j], 0, 0, 0);
    __syncthreads();
  }

  int fq = lane >> 4;
  #pragma unroll
  for (int i = 0; i < 4; ++i) {
    #pragma unroll
    for (int j = 0; j < 4; ++j) {
      #pragma unroll
      for (int r = 0; r < 4; ++r) {
        int row = m0 + wm + i * 16 + fq * 4 + r;
        int col = n0 + wn + j * 16 + fr;
        float v = acc[i][j][r] + (bias ? bias[col] : 0.f);
        if (EPI == 0) {
          outf[(size_t)row * N + col] = v;
        } else {
          float ge = 0.5f * v * (1.0f + erff(v * 0.70710678118f));
          outb[(size_t)row * N + col] = f2b(ge);
        }
      }
    }
  }
}

// ---------------- per-(b,head) K transpose: [S][64] -> [64][S] ----------------
__global__ __launch_bounds__(256) void transpose_k(
    const float* __restrict__ k, float* __restrict__ kT)
{
  __shared__ float tile[32][33];
  int bh = blockIdx.z;
  int b = bh / NH_, hh = bh % NH_;
  const float* src = k + (size_t)b * S_ * H_ + hh * DH_;
  float* dst = kT + (size_t)bh * DH_ * S_;
  int s0 = blockIdx.x * 32, d0 = blockIdx.y * 32;
  int x = threadIdx.x, y = threadIdx.y;
  #pragma unroll
  for (int i = 0; i < 4; ++i)
    tile[y + i * 8][x] = src[(size_t)(s0 + y + i * 8) * H_ + d0 + x];
  __syncthreads();
  #pragma unroll
  for (int i = 0; i < 4; ++i)
    dst[(size_t)(d0 + y + i * 8) * S_ + s0 + x] = tile[x][y + i * 8];
}

// ---------------- flash attention (fp32 vector, online softmax) ---------------
__global__ __launch_bounds__(256) void flash_attn(
    const float* __restrict__ q, const float* __restrict__ kT,
    const float* __restrict__ v, const float* __restrict__ mask,
    float* __restrict__ ctx)
{
  __shared__ float sq[4][64];
  __shared__ float sp[4][64];
  int lane = threadIdx.x & 63, wid = threadIdx.x >> 6;
  int gw = blockIdx.x * 4 + wid;          // one wave = one q row
  int b = gw >> 15;                        // / (NH_*S_)
  int rem = gw & 32767;
  int hh = rem >> 11;                      // / S_
  int qs = rem & 2047;
  int row = b * S_ + qs;
  int off = hh * DH_;
  const float LOG2E = 1.4426950408889634f;
  float qv = q[(size_t)row * H_ + off + lane] * (0.125f * LOG2E);
  sq[wid][lane] = qv;
  const float* Kt = kT + (size_t)(b * NH_ + hh) * DH_ * S_;   // [64][S]
  const float* Vb = v + (size_t)b * S_ * H_ + off;            // [S] rows, stride H
  const float* mrow = mask + (size_t)b * S_;

  float mx = -3.0e38f, l = 0.f, o = 0.f;
  for (int t0 = 0; t0 < S_; t0 += 64) {
    float s0 = 0.f, s1 = 0.f, s2 = 0.f, s3 = 0.f;
    int kc = t0 + lane;
    #pragma unroll
    for (int d = 0; d < 64; d += 4) {
      s0 += sq[wid][d + 0] * Kt[(size_t)(d + 0) * S_ + kc];
      s1 += sq[wid][d + 1] * Kt[(size_t)(d + 1) * S_ + kc];
      s2 += sq[wid][d + 2] * Kt[(size_t)(d + 2) * S_ + kc];
      s3 += sq[wid][d + 3] * Kt[(size_t)(d + 3) * S_ + kc];
    }
    float s = (s0 + s1) + (s2 + s3);
    s += (1.0f - mrow[kc]) * (-10000.0f * LOG2E);   // mask (zeros here, kept general)
    float tm = s;
    #pragma unroll
    for (int d2 = 32; d2; d2 >>= 1) tm = fmaxf(tm, __shfl_xor(tm, d2));
    float mn = fmaxf(mx, tm);
    float p = exp2f(s - mn);
    float corr = exp2f(mx - mn);
    float ps = p;
    #pragma unroll
    for (int d2 = 32; d2; d2 >>= 1) ps += __shfl_xor(ps, d2);
    l = l * corr + ps;
    mx = mn;
    sp[wid][lane] = p;
    o *= corr;
    #pragma unroll 16
    for (int kk = 0; kk < 64; ++kk) {
      o += sp[wid][kk] * Vb[(size_t)(t0 + kk) * H_ + lane];
    }
  }
  ctx[(size_t)row * H_ + off + lane] = o / l;
}

// ---------------- fused (x[+y]) LayerNorm -> f32 and/or bf16 ------------------
__global__ __launch_bounds__(256) void add_ln(
    const float* __restrict__ x, const float* __restrict__ y,
    const float* __restrict__ g, const float* __restrict__ bb,
    float* __restrict__ outf, unsigned short* __restrict__ outb)
{
  __shared__ float a1[4], a2[4];
  int row = blockIdx.x, t = threadIdx.x;
  const float* xr = x + (size_t)row * H_;
  const float* yr = y ? y + (size_t)row * H_ : nullptr;
  float vals[4];
  float s1 = 0.f, s2 = 0.f;
  #pragma unroll
  for (int i = 0; i < 4; ++i) {
    int c = t + i * 256;
    float vv = xr[c] + (yr ? yr[c] : 0.f);
    vals[i] = vv; s1 += vv; s2 += vv * vv;
  }
  #pragma unroll
  for (int d = 32; d; d >>= 1) { s1 += __shfl_xor(s1, d); s2 += __shfl_xor(s2, d); }
  if ((t & 63) == 0) { a1[t >> 6] = s1; a2[t >> 6] = s2; }
  __syncthreads();
  s1 = a1[0] + a1[1] + a1[2] + a1[3];
  s2 = a2[0] + a2[1] + a2[2] + a2[3];
  float mean = s1 * (1.0f / H_);
  float var = s2 * (1.0f / H_) - mean * mean;
  float inv = rsqrtf(var + 1e-5f);
  #pragma unroll
  for (int i = 0; i < 4; ++i) {
    int c = t + i * 256;
    float yv = (vals[i] - mean) * inv * g[c] + bb[c];
    if (outf) outf[(size_t)row * H_ + c] = yv;
    if (outb) outb[(size_t)row * H_ + c] = f2b(yv);
  }
}

// ------------------------------- launcher -------------------------------------
extern "C" void kernel_launch(void* const* d_in, const int* in_sizes, int n_in,
                              void* d_out, int out_size, void* d_ws, size_t ws_size,
                              hipStream_t stream) {
  const int*   ids  = (const int*)d_in[0];
  const float* mask = (const float*)d_in[1];
  const float* tok  = (const float*)d_in[2];
  const float* pos  = (const float*)d_in[3];
  const float* Wq   = (const float*)d_in[4];
  const float* bq   = (const float*)d_in[5];
  const float* Wk   = (const float*)d_in[6];
  const float* bk   = (const float*)d_in[7];
  const float* Wv   = (const float*)d_in[8];
  const float* bv   = (const float*)d_in[9];
  const float* Wi   = (const float*)d_in[10];
  const float* bi   = (const float*)d_in[11];
  const float* Wo   = (const float*)d_in[12];
  const float* bo   = (const float*)d_in[13];
  const float* ln1g = (const float*)d_in[14];
  const float* ln1b = (const float*)d_in[15];
  const float* ln2g = (const float*)d_in[16];
  const float* ln2b = (const float*)d_in[17];
  const float* lnfg = (const float*)d_in[18];
  const float* lnfb = (const float*)d_in[19];
  const float* Wlm  = (const float*)d_in[20];
  float* out = (float*)d_out;

  char* w = (char*)d_ws;
  size_t off = 0;
  auto alloc = [&](size_t bytes) { void* p = w + off; off = (off + bytes + 255) & ~(size_t)255; return p; };
  float* h     = (float*)alloc((size_t)M_ * H_ * 4);
  float* qf    = (float*)alloc((size_t)M_ * H_ * 4);
  float* kf    = (float*)alloc((size_t)M_ * H_ * 4);
  float* vf    = (float*)alloc((size_t)M_ * H_ * 4);
  float* kTb   = (float*)alloc((size_t)B_ * NH_ * DH_ * S_ * 4);
  float* ctxb  = (float*)alloc((size_t)M_ * H_ * 4);
  unsigned short* xbf   = (unsigned short*)alloc((size_t)M_ * H_ * 2);
  unsigned short* midbf = (unsigned short*)alloc((size_t)M_ * I_ * 2);

  embed_kernel<<<dim3(M_, H_ / 256), 256, 0, stream>>>(ids, tok, pos, h, xbf);

  for (int l = 0; l < L_; ++l) {
    const float* Wq_l = Wq + (size_t)l * H_ * H_;
    const float* Wk_l = Wk + (size_t)l * H_ * H_;
    const float* Wv_l = Wv + (size_t)l * H_ * H_;
    const float* Wi_l = Wi + (size_t)l * I_ * H_;
    const float* Wo_l = Wo + (size_t)l * H_ * I_;

    gemm_bt<0><<<dim3(M_ / 128, H_ / 128), 256, 0, stream>>>(xbf, Wq_l, bq + l * H_, qf, nullptr, M_, H_, H_);
    gemm_bt<0><<<dim3(M_ / 128, H_ / 128), 256, 0, stream>>>(xbf, Wk_l, bk + l * H_, kf, nullptr, M_, H_, H_);
    gemm_bt<0><<<dim3(M_ / 128, H_ / 128), 256, 0, stream>>>(xbf, Wv_l, bv + l * H_, vf, nullptr, M_, H_, H_);

    transpose_k<<<dim3(S_ / 32, DH_ / 32, B_ * NH_), dim3(32, 8), 0, stream>>>(kf, kTb);
    flash_attn<<<dim3(B_ * NH_ * S_ / 4), 256, 0, stream>>>(qf, kTb, vf, mask, ctxb);

    add_ln<<<dim3(M_), 256, 0, stream>>>(h, ctxb, ln1g + l * H_, ln1b + l * H_, h, xbf);

    gemm_bt<1><<<dim3(M_ / 128, I_ / 128), 256, 0, stream>>>(xbf, Wi_l, bi + l * I_, nullptr, midbf, M_, I_, H_);
    gemm_bt<0><<<dim3(M_ / 128, H_ / 128), 256, 0, stream>>>(midbf, Wo_l, bo + l * H_, ctxb, nullptr, M_, H_, I_);

    add_ln<<<dim3(M_), 256, 0, stream>>>(h, ctxb, ln2g + l * H_, ln2b + l * H_, h, xbf);
  }

  add_ln<<<dim3(M_), 256, 0, stream>>>(h, nullptr, lnfg, lnfb, nullptr, xbf);
  gemm_bt<0><<<dim3(M_ / 128, V_ / 128), 256, 0, stream>>>(xbf, Wlm, nullptr, out, nullptr, M_, V_, H_);
}

// Round 2
// 5145.998 us; speedup vs baseline: 5.2418x; 5.2418x over previous
//
#include <hip/hip_runtime.h>
#include <hip/hip_bf16.h>

#define V_ 32000
#define H_ 1024
#define NH_ 16
#define I_ 4096
#define L_ 8
#define B_ 2
#define S_ 2048
#define DH_ 64
#define M_ 4096  // B_*S_

typedef __attribute__((ext_vector_type(4))) float f32x4;
typedef __attribute__((ext_vector_type(8))) short s16x8;

__device__ __forceinline__ unsigned short f2b(float f) {
  union { float f; unsigned u; } x; x.f = f;
  return (unsigned short)((x.u + 0x7FFFu + ((x.u >> 16) & 1u)) >> 16);
}

// ---------------- embedding: h = tok[ids] + pos, also bf16 copy ----------------
__global__ __launch_bounds__(256) void embed_kernel(
    const int* __restrict__ ids, const float* __restrict__ tok,
    const float* __restrict__ pos, float* __restrict__ h,
    unsigned short* __restrict__ xbf)
{
  int row = blockIdx.x;
  int c = blockIdx.y * 256 + threadIdx.x;
  int id = ids[row];
  int s = row & (S_ - 1);
  float v = tok[(size_t)id * H_ + c] + pos[(size_t)s * H_ + c];
  h[(size_t)row * H_ + c] = v;
  xbf[(size_t)row * H_ + c] = f2b(v);
}

// ---------------- GEMM: out[M,N] = A[M,K](bf16) @ W[N,K]^T (f32->bf16) + bias --
// EPI 0: f32 out + bias.  EPI 1: gelu(x+bias) -> bf16.  EPI 2: bias -> bf16.
template<int EPI>
__global__ __launch_bounds__(256) void gemm_bt(
    const unsigned short* __restrict__ A, const float* __restrict__ Wt,
    const float* __restrict__ bias, float* __restrict__ outf,
    unsigned short* __restrict__ outb, int M, int N, int K)
{
  __shared__ unsigned short As[128][32];
  __shared__ unsigned short Bs[128][32];
  int t = threadIdx.x;
  int lane = t & 63, wid = t >> 6;
  int m0 = blockIdx.x * 128, n0 = blockIdx.y * 128;
  int wm = (wid >> 1) * 64, wn = (wid & 1) * 64;

  f32x4 acc[4][4] = {};

  int ar = t >> 2, ac = (t & 3) * 8;   // A staging: 2 rounds of 16B/thread
  int wr = t >> 3, wc = (t & 7) * 4;   // W staging: 4 rounds of float4/thread
  int fr = lane & 15, kh = (lane >> 4) * 8;

  for (int k0 = 0; k0 < K; k0 += 32) {
    #pragma unroll
    for (int r = 0; r < 2; ++r) {
      const int4 d = *(const int4*)(A + (size_t)(m0 + r * 64 + ar) * K + k0 + ac);
      *(int4*)(&As[r * 64 + ar][ac]) = d;
    }
    #pragma unroll
    for (int r = 0; r < 4; ++r) {
      const float4 d = *(const float4*)(Wt + (size_t)(n0 + r * 32 + wr) * K + k0 + wc);
      ushort4 b4;
      b4.x = f2b(d.x); b4.y = f2b(d.y); b4.z = f2b(d.z); b4.w = f2b(d.w);
      *(ushort4*)(&Bs[r * 32 + wr][wc]) = b4;
    }
    __syncthreads();
    s16x8 af[4], bfr[4];
    #pragma unroll
    for (int i = 0; i < 4; ++i) af[i]  = *(const s16x8*)(&As[wm + i * 16 + fr][kh]);
    #pragma unroll
    for (int j = 0; j < 4; ++j) bfr[j] = *(const s16x8*)(&Bs[wn + j * 16 + fr][kh]);
    #pragma unroll
    for (int i = 0; i < 4; ++i)
      #pragma unroll
      for (int j = 0; j < 4; ++j)
        acc[i][j] = __builtin_amdgcn_mfma_f32_16x16x32_bf16(af[i], bfr[j], acc[i][j], 0, 0, 0);
    __syncthreads();
  }

  int fq = lane >> 4;
  #pragma unroll
  for (int i = 0; i < 4; ++i) {
    #pragma unroll
    for (int j = 0; j < 4; ++j) {
      #pragma unroll
      for (int r = 0; r < 4; ++r) {
        int row = m0 + wm + i * 16 + fq * 4 + r;
        int col = n0 + wn + j * 16 + fr;
        float v = acc[i][j][r] + (bias ? bias[col] : 0.f);
        if (EPI == 0) {
          outf[(size_t)row * N + col] = v;
        } else if (EPI == 1) {
          float ge = 0.5f * v * (1.0f + erff(v * 0.70710678118f));
          outb[(size_t)row * N + col] = f2b(ge);
        } else {
          outb[(size_t)row * N + col] = f2b(v);
        }
      }
    }
  }
}

// ---------------- per-(b,head) V transpose (bf16): [S][64] -> [64][S] ---------
__global__ __launch_bounds__(256) void transpose_v_bf16(
    const unsigned short* __restrict__ v, unsigned short* __restrict__ vT)
{
  __shared__ unsigned short tile[32][34];
  int bh = blockIdx.z;
  int b = bh >> 4, hh = bh & 15;
  const unsigned short* src = v + (size_t)b * S_ * H_ + hh * DH_;
  unsigned short* dst = vT + (size_t)bh * DH_ * S_;
  int s0 = blockIdx.x * 32, d0 = blockIdx.y * 32;
  int x = threadIdx.x, y = threadIdx.y;
  #pragma unroll
  for (int i = 0; i < 4; ++i)
    tile[y + i * 8][x] = src[(size_t)(s0 + y + i * 8) * H_ + d0 + x];
  __syncthreads();
  #pragma unroll
  for (int i = 0; i < 4; ++i)
    dst[(size_t)(d0 + y + i * 8) * S_ + s0 + x] = tile[x][y + i * 8];
}

// ---------------- MFMA flash attention (bf16, online softmax) -----------------
// Block: one (b,head), 64 q rows (4 waves x 16). Loop KV in 64-col tiles.
#define KB_ 64
__global__ __launch_bounds__(256) void flash_mfma(
    const unsigned short* __restrict__ qb,  // [M][H] bf16
    const unsigned short* __restrict__ kb,  // [M][H] bf16
    const unsigned short* __restrict__ vtb, // [B*NH][DH][S] bf16
    const float* __restrict__ mask,         // [B][S]
    float* __restrict__ ctx)                // [M][H] f32
{
  __shared__ unsigned short Ks[KB_][72];     // K tile [k][d], padded
  __shared__ unsigned short Vs[DH_][72];     // V^T tile [d][k], padded
  __shared__ unsigned short Ps[4][16][72];   // per-wave P tile [q][k], padded
  __shared__ float maskl[S_];

  const float SCL = 0.125f * 1.4426950408889634f;  // 1/sqrt(64) * log2(e)
  int t = threadIdx.x, lane = t & 63, wid = t >> 6;
  int blk = blockIdx.x;
  int bh = blk >> 5, qt = blk & 31;
  int b = bh >> 4, hh = bh & 15;
  int row0 = b * S_ + qt * 64 + wid * 16;
  int fr = lane & 15, hi = lane >> 4;

  for (int i = t; i < S_; i += 256)
    maskl[i] = (1.0f - mask[b * S_ + i]) * (-10000.0f * 1.4426950408889634f);

  // Q fragments (held in registers for the whole kernel)
  s16x8 qf[2];
  {
    const unsigned short* qrow = qb + (size_t)(row0 + fr) * H_ + hh * DH_;
    qf[0] = *(const s16x8*)(qrow + hi * 8);
    qf[1] = *(const s16x8*)(qrow + 32 + hi * 8);
  }

  float m_run[4], l_run[4];
  f32x4 octx[4] = {};
  #pragma unroll
  for (int r = 0; r < 4; ++r) { m_run[r] = -3.0e38f; l_run[r] = 0.f; }

  const unsigned short* Kbase = kb + (size_t)b * S_ * H_ + hh * DH_;
  const unsigned short* Vbase = vtb + (size_t)bh * DH_ * S_;

  int sr = t >> 2, sc4 = (t & 3) * 16;  // staging: 4 threads/row, 32B each

  for (int t0 = 0; t0 < S_; t0 += KB_) {
    // stage K tile and V^T tile
    {
      const unsigned short* ksrc = Kbase + (size_t)(t0 + sr) * H_ + sc4;
      *(int4*)(&Ks[sr][sc4])     = *(const int4*)ksrc;
      *(int4*)(&Ks[sr][sc4 + 8]) = *(const int4*)(ksrc + 8);
      const unsigned short* vsrc = Vbase + (size_t)sr * S_ + t0 + sc4;
      *(int4*)(&Vs[sr][sc4])     = *(const int4*)vsrc;
      *(int4*)(&Vs[sr][sc4 + 8]) = *(const int4*)(vsrc + 8);
    }
    __syncthreads();

    // QK^T: S-tile 16q x 64k  (4 col-groups)
    f32x4 sacc[4] = {};
    #pragma unroll
    for (int g = 0; g < 4; ++g) {
      #pragma unroll
      for (int i = 0; i < 2; ++i) {
        s16x8 kf = *(const s16x8*)(&Ks[g * 16 + fr][i * 32 + hi * 8]);
        sacc[g] = __builtin_amdgcn_mfma_f32_16x16x32_bf16(qf[i], kf, sacc[g], 0, 0, 0);
      }
    }

    // online softmax (base-2). C layout: col=fr (k), row=hi*4+r (q)
    float sc[4][4], tm[4];
    #pragma unroll
    for (int r = 0; r < 4; ++r) tm[r] = -3.0e38f;
    #pragma unroll
    for (int g = 0; g < 4; ++g) {
      float mk = maskl[t0 + g * 16 + fr];
      #pragma unroll
      for (int r = 0; r < 4; ++r) {
        float v = sacc[g][r] * SCL + mk;
        sc[g][r] = v;
        tm[r] = fmaxf(tm[r], v);
      }
    }
    #pragma unroll
    for (int msk = 8; msk; msk >>= 1)
      #pragma unroll
      for (int r = 0; r < 4; ++r) tm[r] = fmaxf(tm[r], __shfl_xor(tm[r], msk));

    float corr[4], ps[4] = {0.f, 0.f, 0.f, 0.f};
    #pragma unroll
    for (int r = 0; r < 4; ++r) {
      float mn = fmaxf(m_run[r], tm[r]);
      corr[r] = exp2f(m_run[r] - mn);
      m_run[r] = mn;
    }
    #pragma unroll
    for (int g = 0; g < 4; ++g)
      #pragma unroll
      for (int r = 0; r < 4; ++r) {
        float p = exp2f(sc[g][r] - m_run[r]);
        sc[g][r] = p;
        ps[r] += p;
      }
    #pragma unroll
    for (int msk = 8; msk; msk >>= 1)
      #pragma unroll
      for (int r = 0; r < 4; ++r) ps[r] += __shfl_xor(ps[r], msk);
    #pragma unroll
    for (int r = 0; r < 4; ++r) l_run[r] = l_run[r] * corr[r] + ps[r];

    // P -> per-wave LDS (C layout -> A layout bounce)
    #pragma unroll
    for (int g = 0; g < 4; ++g)
      #pragma unroll
      for (int r = 0; r < 4; ++r)
        Ps[wid][hi * 4 + r][g * 16 + fr] = f2b(sc[g][r]);

    // rescale running context
    #pragma unroll
    for (int dg = 0; dg < 4; ++dg)
      #pragma unroll
      for (int r = 0; r < 4; ++r) octx[dg][r] *= corr[r];

    // PV: ctx-tile 16q x 64d
    #pragma unroll
    for (int kc = 0; kc < 2; ++kc) {
      s16x8 pf = *(const s16x8*)(&Ps[wid][fr][kc * 32 + hi * 8]);
      #pragma unroll
      for (int dg = 0; dg < 4; ++dg) {
        s16x8 vf2 = *(const s16x8*)(&Vs[dg * 16 + fr][kc * 32 + hi * 8]);
        octx[dg] = __builtin_amdgcn_mfma_f32_16x16x32_bf16(pf, vf2, octx[dg], 0, 0, 0);
      }
    }
    __syncthreads();  // protect Ks/Vs before next stage
  }

  float inv[4];
  #pragma unroll
  for (int r = 0; r < 4; ++r) inv[r] = 1.0f / l_run[r];
  #pragma unroll
  for (int dg = 0; dg < 4; ++dg)
    #pragma unroll
    for (int r = 0; r < 4; ++r)
      ctx[(size_t)(row0 + hi * 4 + r) * H_ + hh * DH_ + dg * 16 + fr] = octx[dg][r] * inv[r];
}

// ---------------- fused (x[+y]) LayerNorm -> f32 and/or bf16 ------------------
__global__ __launch_bounds__(256) void add_ln(
    const float* __restrict__ x, const float* __restrict__ y,
    const float* __restrict__ g, const float* __restrict__ bb,
    float* __restrict__ outf, unsigned short* __restrict__ outb)
{
  __shared__ float a1[4], a2[4];
  int row = blockIdx.x, t = threadIdx.x;
  const float* xr = x + (size_t)row * H_;
  const float* yr = y ? y + (size_t)row * H_ : nullptr;
  float vals[4];
  float s1 = 0.f, s2 = 0.f;
  #pragma unroll
  for (int i = 0; i < 4; ++i) {
    int c = t + i * 256;
    float vv = xr[c] + (yr ? yr[c] : 0.f);
    vals[i] = vv; s1 += vv; s2 += vv * vv;
  }
  #pragma unroll
  for (int d = 32; d; d >>= 1) { s1 += __shfl_xor(s1, d); s2 += __shfl_xor(s2, d); }
  if ((t & 63) == 0) { a1[t >> 6] = s1; a2[t >> 6] = s2; }
  __syncthreads();
  s1 = a1[0] + a1[1] + a1[2] + a1[3];
  s2 = a2[0] + a2[1] + a2[2] + a2[3];
  float mean = s1 * (1.0f / H_);
  float var = s2 * (1.0f / H_) - mean * mean;
  float inv = rsqrtf(var + 1e-5f);
  #pragma unroll
  for (int i = 0; i < 4; ++i) {
    int c = t + i * 256;
    float yv = (vals[i] - mean) * inv * g[c] + bb[c];
    if (outf) outf[(size_t)row * H_ + c] = yv;
    if (outb) outb[(size_t)row * H_ + c] = f2b(yv);
  }
}

// ------------------------------- launcher -------------------------------------
extern "C" void kernel_launch(void* const* d_in, const int* in_sizes, int n_in,
                              void* d_out, int out_size, void* d_ws, size_t ws_size,
                              hipStream_t stream) {
  const int*   ids  = (const int*)d_in[0];
  const float* mask = (const float*)d_in[1];
  const float* tok  = (const float*)d_in[2];
  const float* pos  = (const float*)d_in[3];
  const float* Wq   = (const float*)d_in[4];
  const float* bq   = (const float*)d_in[5];
  const float* Wk   = (const float*)d_in[6];
  const float* bk   = (const float*)d_in[7];
  const float* Wv   = (const float*)d_in[8];
  const float* bv   = (const float*)d_in[9];
  const float* Wi   = (const float*)d_in[10];
  const float* bi   = (const float*)d_in[11];
  const float* Wo   = (const float*)d_in[12];
  const float* bo   = (const float*)d_in[13];
  const float* ln1g = (const float*)d_in[14];
  const float* ln1b = (const float*)d_in[15];
  const float* ln2g = (const float*)d_in[16];
  const float* ln2b = (const float*)d_in[17];
  const float* lnfg = (const float*)d_in[18];
  const float* lnfb = (const float*)d_in[19];
  const float* Wlm  = (const float*)d_in[20];
  float* out = (float*)d_out;

  char* w = (char*)d_ws;
  size_t off = 0;
  auto alloc = [&](size_t bytes) { void* p = w + off; off = (off + bytes + 255) & ~(size_t)255; return p; };
  float* h     = (float*)alloc((size_t)M_ * H_ * 4);
  float* ctxb  = (float*)alloc((size_t)M_ * H_ * 4);
  unsigned short* qbb   = (unsigned short*)alloc((size_t)M_ * H_ * 2);
  unsigned short* kbb   = (unsigned short*)alloc((size_t)M_ * H_ * 2);
  unsigned short* vbb   = (unsigned short*)alloc((size_t)M_ * H_ * 2);
  unsigned short* vtb   = (unsigned short*)alloc((size_t)B_ * NH_ * DH_ * S_ * 2);
  unsigned short* xbf   = (unsigned short*)alloc((size_t)M_ * H_ * 2);
  unsigned short* midbf = (unsigned short*)alloc((size_t)M_ * I_ * 2);

  embed_kernel<<<dim3(M_, H_ / 256), 256, 0, stream>>>(ids, tok, pos, h, xbf);

  for (int l = 0; l < L_; ++l) {
    const float* Wq_l = Wq + (size_t)l * H_ * H_;
    const float* Wk_l = Wk + (size_t)l * H_ * H_;
    const float* Wv_l = Wv + (size_t)l * H_ * H_;
    const float* Wi_l = Wi + (size_t)l * I_ * H_;
    const float* Wo_l = Wo + (size_t)l * H_ * I_;

    gemm_bt<2><<<dim3(M_ / 128, H_ / 128), 256, 0, stream>>>(xbf, Wq_l, bq + l * H_, nullptr, qbb, M_, H_, H_);
    gemm_bt<2><<<dim3(M_ / 128, H_ / 128), 256, 0, stream>>>(xbf, Wk_l, bk + l * H_, nullptr, kbb, M_, H_, H_);
    gemm_bt<2><<<dim3(M_ / 128, H_ / 128), 256, 0, stream>>>(xbf, Wv_l, bv + l * H_, nullptr, vbb, M_, H_, H_);

    transpose_v_bf16<<<dim3(S_ / 32, DH_ / 32, B_ * NH_), dim3(32, 8), 0, stream>>>(vbb, vtb);
    flash_mfma<<<dim3(B_ * NH_ * S_ / 64), 256, 0, stream>>>(qbb, kbb, vtb, mask, ctxb);

    add_ln<<<dim3(M_), 256, 0, stream>>>(h, ctxb, ln1g + l * H_, ln1b + l * H_, h, xbf);

    gemm_bt<1><<<dim3(M_ / 128, I_ / 128), 256, 0, stream>>>(xbf, Wi_l, bi + l * I_, nullptr, midbf, M_, I_, H_);
    gemm_bt<0><<<dim3(M_ / 128, H_ / 128), 256, 0, stream>>>(midbf, Wo_l, bo + l * H_, ctxb, nullptr, M_, H_, I_);

    add_ln<<<dim3(M_), 256, 0, stream>>>(h, ctxb, ln2g + l * H_, ln2b + l * H_, h, xbf);
  }

  add_ln<<<dim3(M_), 256, 0, stream>>>(h, nullptr, lnfg, lnfb, nullptr, xbf);
  gemm_bt<0><<<dim3(M_ / 128, V_ / 128), 256, 0, stream>>>(xbf, Wlm, nullptr, out, nullptr, M_, V_, H_);
}

// Round 3
// 3653.608 us; speedup vs baseline: 7.3828x; 1.4085x over previous
//
#include <hip/hip_runtime.h>
#include <hip/hip_bf16.h>

#define V_ 32000
#define H_ 1024
#define NH_ 16
#define I_ 4096
#define L_ 8
#define B_ 2
#define S_ 2048
#define DH_ 64
#define M_ 4096   // B_*S_
#define QS_ 3072  // fused QKV row stride

typedef __attribute__((ext_vector_type(4))) float f32x4;
typedef __attribute__((ext_vector_type(8))) short s16x8;

__device__ __forceinline__ unsigned short f2b(float f) {
  union { float f; unsigned u; } x; x.f = f;
  return (unsigned short)((x.u + 0x7FFFu + ((x.u >> 16) & 1u)) >> 16);
}

__device__ __forceinline__ void gl_lds16(const unsigned short* g, unsigned short* l) {
  __builtin_amdgcn_global_load_lds(
      (__attribute__((address_space(1))) const void*)g,
      (__attribute__((address_space(3))) void*)l, 16, 0, 0);
}

// ---------------- weight f32 -> bf16 flat convert ------------------------------
__global__ __launch_bounds__(256) void wcvt(const float* __restrict__ src,
                                            unsigned short* __restrict__ dst) {
  int i = (blockIdx.x * 256 + threadIdx.x) * 4;
  float4 v = *(const float4*)(src + i);
  ushort4 b;
  b.x = f2b(v.x); b.y = f2b(v.y); b.z = f2b(v.z); b.w = f2b(v.w);
  *(ushort4*)(dst + i) = b;
}

// concat per-layer Wq|Wk|Wv (each [H][H]) -> dst [3H][H] bf16
__global__ __launch_bounds__(256) void qkvcat(const float* __restrict__ q,
                                              const float* __restrict__ k,
                                              const float* __restrict__ v,
                                              unsigned short* __restrict__ dst) {
  int i = (blockIdx.x * 256 + threadIdx.x) * 4;
  const float* s; int off;
  if (i < H_ * H_)          { s = q; off = i; }
  else if (i < 2 * H_ * H_) { s = k; off = i - H_ * H_; }
  else                      { s = v; off = i - 2 * H_ * H_; }
  float4 vv = *(const float4*)(s + off);
  ushort4 b;
  b.x = f2b(vv.x); b.y = f2b(vv.y); b.z = f2b(vv.z); b.w = f2b(vv.w);
  *(ushort4*)(dst + i) = b;
}

// concat biases bq|bk|bv per layer -> [L][3H] f32
__global__ __launch_bounds__(256) void bcat(const float* __restrict__ bq,
                                            const float* __restrict__ bk,
                                            const float* __restrict__ bv,
                                            float* __restrict__ dst) {
  int i = blockIdx.x * 256 + threadIdx.x;       // L_*3*H_ total
  int l = i / (3 * H_), r = i - l * 3 * H_;
  int p = r >> 10, c = r & (H_ - 1);
  const float* s = (p == 0) ? bq : ((p == 1) ? bk : bv);
  dst[i] = s[l * H_ + c];
}

// ---------------- embedding: h = tok[ids] + pos, also bf16 copy ----------------
__global__ __launch_bounds__(256) void embed_kernel(
    const int* __restrict__ ids, const float* __restrict__ tok,
    const float* __restrict__ pos, float* __restrict__ h,
    unsigned short* __restrict__ xbf)
{
  int row = blockIdx.x;
  int c = blockIdx.y * 256 + threadIdx.x;
  int id = ids[row];
  int s = row & (S_ - 1);
  float v = tok[(size_t)id * H_ + c] + pos[(size_t)s * H_ + c];
  h[(size_t)row * H_ + c] = v;
  xbf[(size_t)row * H_ + c] = f2b(v);
}

// ---------------- GEMM (m97 structure): out[M,N] = A[M,K] @ W[N,K]^T + bias ----
// A, W bf16. EPI 0: f32 out + bias.  EPI 1: gelu(x+bias) -> bf16.  EPI 2: bias -> bf16.
template<int EPI>
__global__ __launch_bounds__(256) void gemm_bt(
    const unsigned short* __restrict__ A, const unsigned short* __restrict__ Wb,
    const float* __restrict__ bias, float* __restrict__ outf,
    unsigned short* __restrict__ outb, int M, int N, int K)
{
  __shared__ unsigned short As[128][32];
  __shared__ unsigned short Bs[128][32];
  int t = threadIdx.x;
  int lane = t & 63, wid = t >> 6;
  int m0 = blockIdx.x * 128, n0 = blockIdx.y * 128;
  int wm = (wid >> 1) * 64, wn = (wid & 1) * 64;
  int fr = lane & 15, kh = (lane >> 4) * 8;
  int lrow = lane >> 2, lcol = (lane & 3) * 8;  // DMA chunk: 16 rows x 32 cols

  f32x4 acc[4][4] = {};

  const unsigned short* Abase = A  + (size_t)(m0 + wid * 32 + lrow) * K + lcol;
  const unsigned short* Bbase = Wb + (size_t)(n0 + wid * 32 + lrow) * K + lcol;
  unsigned short* AL0 = &As[wid * 32][0];
  unsigned short* AL1 = &As[wid * 32 + 16][0];
  unsigned short* BL0 = &Bs[wid * 32][0];
  unsigned short* BL1 = &Bs[wid * 32 + 16][0];

  for (int k0 = 0; k0 < K; k0 += 32) {
    gl_lds16(Abase + k0,                     AL0);
    gl_lds16(Abase + k0 + (size_t)16 * K,    AL1);
    gl_lds16(Bbase + k0,                     BL0);
    gl_lds16(Bbase + k0 + (size_t)16 * K,    BL1);
    __syncthreads();
    s16x8 af[4], bfr[4];
    #pragma unroll
    for (int i = 0; i < 4; ++i) af[i]  = *(const s16x8*)(&As[wm + i * 16 + fr][kh]);
    #pragma unroll
    for (int j = 0; j < 4; ++j) bfr[j] = *(const s16x8*)(&Bs[wn + j * 16 + fr][kh]);
    #pragma unroll
    for (int i = 0; i < 4; ++i)
      #pragma unroll
      for (int j = 0; j < 4; ++j)
        acc[i][j] = __builtin_amdgcn_mfma_f32_16x16x32_bf16(af[i], bfr[j], acc[i][j], 0, 0, 0);
    __syncthreads();
  }

  int fq = lane >> 4;
  #pragma unroll
  for (int i = 0; i < 4; ++i) {
    #pragma unroll
    for (int j = 0; j < 4; ++j) {
      #pragma unroll
      for (int r = 0; r < 4; ++r) {
        int row = m0 + wm + i * 16 + fq * 4 + r;
        int col = n0 + wn + j * 16 + fr;
        float v = acc[i][j][r] + (bias ? bias[col] : 0.f);
        if (EPI == 0) {
          outf[(size_t)row * N + col] = v;
        } else if (EPI == 1) {
          float ge = 0.5f * v * (1.0f + erff(v * 0.70710678118f));
          outb[(size_t)row * N + col] = f2b(ge);
        } else {
          outb[(size_t)row * N + col] = f2b(v);
        }
      }
    }
  }
}

// ---------------- per-(b,head) V transpose (bf16): [S][64] -> [64][S] ---------
// src rows have stride QS_ (V slice of fused QKV buffer)
__global__ __launch_bounds__(256) void transpose_v_bf16(
    const unsigned short* __restrict__ v, unsigned short* __restrict__ vT)
{
  __shared__ unsigned short tile[32][34];
  int bh = blockIdx.z;
  int b = bh >> 4, hh = bh & 15;
  const unsigned short* src = v + (size_t)b * S_ * QS_ + hh * DH_;
  unsigned short* dst = vT + (size_t)bh * DH_ * S_;
  int s0 = blockIdx.x * 32, d0 = blockIdx.y * 32;
  int x = threadIdx.x, y = threadIdx.y;
  #pragma unroll
  for (int i = 0; i < 4; ++i)
    tile[y + i * 8][x] = src[(size_t)(s0 + y + i * 8) * QS_ + d0 + x];
  __syncthreads();
  #pragma unroll
  for (int i = 0; i < 4; ++i)
    dst[(size_t)(d0 + y + i * 8) * S_ + s0 + x] = tile[x][y + i * 8];
}

// ---------------- MFMA flash attention (bf16, online softmax) -----------------
// Block: one (b,head), 64 q rows (4 waves x 16). Loop KV in 64-col tiles.
// q/k live in the fused QKV buffer (row stride QS_), V^T pre-transposed.
#define KB_ 64
__global__ __launch_bounds__(256) void flash_mfma(
    const unsigned short* __restrict__ qb,  // q slice base
    const unsigned short* __restrict__ kb,  // k slice base
    const unsigned short* __restrict__ vtb, // [B*NH][DH][S] bf16
    const float* __restrict__ mask,         // [B][S]
    float* __restrict__ ctx)                // [M][H] f32
{
  __shared__ unsigned short Ks[KB_][72];     // K tile [k][d], padded
  __shared__ unsigned short Vs[DH_][72];     // V^T tile [d][k], padded
  __shared__ unsigned short Ps[4][16][72];   // per-wave P tile [q][k], padded
  __shared__ float maskl[S_];

  const float SCL = 0.125f * 1.4426950408889634f;  // 1/sqrt(64) * log2(e)
  int t = threadIdx.x, lane = t & 63, wid = t >> 6;
  int blk = blockIdx.x;
  int bh = blk >> 5, qt = blk & 31;
  int b = bh >> 4, hh = bh & 15;
  int row0 = b * S_ + qt * 64 + wid * 16;
  int fr = lane & 15, hi = lane >> 4;

  for (int i = t; i < S_; i += 256)
    maskl[i] = (1.0f - mask[b * S_ + i]) * (-10000.0f * 1.4426950408889634f);

  s16x8 qf[2];
  {
    const unsigned short* qrow = qb + (size_t)(row0 + fr) * QS_ + hh * DH_;
    qf[0] = *(const s16x8*)(qrow + hi * 8);
    qf[1] = *(const s16x8*)(qrow + 32 + hi * 8);
  }

  float m_run[4], l_run[4];
  f32x4 octx[4] = {};
  #pragma unroll
  for (int r = 0; r < 4; ++r) { m_run[r] = -3.0e38f; l_run[r] = 0.f; }

  const unsigned short* Kbase = kb + (size_t)b * S_ * QS_ + hh * DH_;
  const unsigned short* Vbase = vtb + (size_t)bh * DH_ * S_;

  int sr = t >> 2, sc4 = (t & 3) * 16;  // staging: 4 threads/row, 32B each

  // prologue: preload tile 0 into registers (T14 async split)
  int4 kreg0, kreg1, vreg0, vreg1;
  {
    const unsigned short* ks = Kbase + (size_t)sr * QS_ + sc4;
    kreg0 = *(const int4*)ks; kreg1 = *(const int4*)(ks + 8);
    const unsigned short* vs = Vbase + (size_t)sr * S_ + sc4;
    vreg0 = *(const int4*)vs; vreg1 = *(const int4*)(vs + 8);
  }

  for (int t0 = 0; t0 < S_; t0 += KB_) {
    // write staged regs -> LDS
    *(int4*)(&Ks[sr][sc4])     = kreg0;
    *(int4*)(&Ks[sr][sc4 + 8]) = kreg1;
    *(int4*)(&Vs[sr][sc4])     = vreg0;
    *(int4*)(&Vs[sr][sc4 + 8]) = vreg1;
    __syncthreads();

    // issue next-tile loads (consumed at next iteration's LDS write)
    if (t0 + KB_ < S_) {
      const unsigned short* ks = Kbase + (size_t)(t0 + KB_ + sr) * QS_ + sc4;
      kreg0 = *(const int4*)ks; kreg1 = *(const int4*)(ks + 8);
      const unsigned short* vs = Vbase + (size_t)sr * S_ + t0 + KB_ + sc4;
      vreg0 = *(const int4*)vs; vreg1 = *(const int4*)(vs + 8);
    }

    // QK^T: S-tile 16q x 64k  (4 col-groups)
    f32x4 sacc[4] = {};
    #pragma unroll
    for (int g = 0; g < 4; ++g) {
      #pragma unroll
      for (int i = 0; i < 2; ++i) {
        s16x8 kf = *(const s16x8*)(&Ks[g * 16 + fr][i * 32 + hi * 8]);
        sacc[g] = __builtin_amdgcn_mfma_f32_16x16x32_bf16(qf[i], kf, sacc[g], 0, 0, 0);
      }
    }

    // online softmax (base-2). C layout: col=fr (k), row=hi*4+r (q)
    float sc[4][4], tm[4];
    #pragma unroll
    for (int r = 0; r < 4; ++r) tm[r] = -3.0e38f;
    #pragma unroll
    for (int g = 0; g < 4; ++g) {
      float mk = maskl[t0 + g * 16 + fr];
      #pragma unroll
      for (int r = 0; r < 4; ++r) {
        float v = sacc[g][r] * SCL + mk;
        sc[g][r] = v;
        tm[r] = fmaxf(tm[r], v);
      }
    }
    #pragma unroll
    for (int msk = 8; msk; msk >>= 1)
      #pragma unroll
      for (int r = 0; r < 4; ++r) tm[r] = fmaxf(tm[r], __shfl_xor(tm[r], msk));

    // T13 defer-max: only rescale when the new tile max exceeds m_run + 8
    bool ok = true;
    #pragma unroll
    for (int r = 0; r < 4; ++r) ok = ok && (tm[r] <= m_run[r] + 8.0f);
    if (!__all(ok)) {
      float corr[4];
      #pragma unroll
      for (int r = 0; r < 4; ++r) {
        float mn = fmaxf(m_run[r], tm[r]);
        corr[r] = exp2f(m_run[r] - mn);
        m_run[r] = mn;
        l_run[r] *= corr[r];
      }
      #pragma unroll
      for (int dg = 0; dg < 4; ++dg)
        #pragma unroll
        for (int r = 0; r < 4; ++r) octx[dg][r] *= corr[r];
    }

    float ps[4] = {0.f, 0.f, 0.f, 0.f};
    #pragma unroll
    for (int g = 0; g < 4; ++g)
      #pragma unroll
      for (int r = 0; r < 4; ++r) {
        float p = exp2f(sc[g][r] - m_run[r]);
        sc[g][r] = p;
        ps[r] += p;
      }
    #pragma unroll
    for (int msk = 8; msk; msk >>= 1)
      #pragma unroll
      for (int r = 0; r < 4; ++r) ps[r] += __shfl_xor(ps[r], msk);
    #pragma unroll
    for (int r = 0; r < 4; ++r) l_run[r] += ps[r];

    // P -> per-wave LDS (C layout -> A layout bounce)
    #pragma unroll
    for (int g = 0; g < 4; ++g)
      #pragma unroll
      for (int r = 0; r < 4; ++r)
        Ps[wid][hi * 4 + r][g * 16 + fr] = f2b(sc[g][r]);

    // PV: ctx-tile 16q x 64d
    #pragma unroll
    for (int kc = 0; kc < 2; ++kc) {
      s16x8 pf = *(const s16x8*)(&Ps[wid][fr][kc * 32 + hi * 8]);
      #pragma unroll
      for (int dg = 0; dg < 4; ++dg) {
        s16x8 vf2 = *(const s16x8*)(&Vs[dg * 16 + fr][kc * 32 + hi * 8]);
        octx[dg] = __builtin_amdgcn_mfma_f32_16x16x32_bf16(pf, vf2, octx[dg], 0, 0, 0);
      }
    }
    __syncthreads();  // protect Ks/Vs/Ps before next stage
  }

  float inv[4];
  #pragma unroll
  for (int r = 0; r < 4; ++r) inv[r] = 1.0f / l_run[r];
  #pragma unroll
  for (int dg = 0; dg < 4; ++dg)
    #pragma unroll
    for (int r = 0; r < 4; ++r)
      ctx[(size_t)(row0 + hi * 4 + r) * H_ + hh * DH_ + dg * 16 + fr] = octx[dg][r] * inv[r];
}

// ---------------- fused (x[+y]) LayerNorm -> f32 and/or bf16 ------------------
__global__ __launch_bounds__(256) void add_ln(
    const float* __restrict__ x, const float* __restrict__ y,
    const float* __restrict__ g, const float* __restrict__ bb,
    float* __restrict__ outf, unsigned short* __restrict__ outb)
{
  __shared__ float a1[4], a2[4];
  int row = blockIdx.x, t = threadIdx.x;
  const float* xr = x + (size_t)row * H_;
  const float* yr = y ? y + (size_t)row * H_ : nullptr;
  float vals[4];
  float s1 = 0.f, s2 = 0.f;
  #pragma unroll
  for (int i = 0; i < 4; ++i) {
    int c = t + i * 256;
    float vv = xr[c] + (yr ? yr[c] : 0.f);
    vals[i] = vv; s1 += vv; s2 += vv * vv;
  }
  #pragma unroll
  for (int d = 32; d; d >>= 1) { s1 += __shfl_xor(s1, d); s2 += __shfl_xor(s2, d); }
  if ((t & 63) == 0) { a1[t >> 6] = s1; a2[t >> 6] = s2; }
  __syncthreads();
  s1 = a1[0] + a1[1] + a1[2] + a1[3];
  s2 = a2[0] + a2[1] + a2[2] + a2[3];
  float mean = s1 * (1.0f / H_);
  float var = s2 * (1.0f / H_) - mean * mean;
  float inv = rsqrtf(var + 1e-5f);
  #pragma unroll
  for (int i = 0; i < 4; ++i) {
    int c = t + i * 256;
    float yv = (vals[i] - mean) * inv * g[c] + bb[c];
    if (outf) outf[(size_t)row * H_ + c] = yv;
    if (outb) outb[(size_t)row * H_ + c] = f2b(yv);
  }
}

// ------------------------------- launcher -------------------------------------
extern "C" void kernel_launch(void* const* d_in, const int* in_sizes, int n_in,
                              void* d_out, int out_size, void* d_ws, size_t ws_size,
                              hipStream_t stream) {
  const int*   ids  = (const int*)d_in[0];
  const float* mask = (const float*)d_in[1];
  const float* tok  = (const float*)d_in[2];
  const float* pos  = (const float*)d_in[3];
  const float* Wq   = (const float*)d_in[4];
  const float* bq   = (const float*)d_in[5];
  const float* Wk   = (const float*)d_in[6];
  const float* bk   = (const float*)d_in[7];
  const float* Wv   = (const float*)d_in[8];
  const float* bv   = (const float*)d_in[9];
  const float* Wi   = (const float*)d_in[10];
  const float* bi   = (const float*)d_in[11];
  const float* Wo   = (const float*)d_in[12];
  const float* bo   = (const float*)d_in[13];
  const float* ln1g = (const float*)d_in[14];
  const float* ln1b = (const float*)d_in[15];
  const float* ln2g = (const float*)d_in[16];
  const float* ln2b = (const float*)d_in[17];
  const float* lnfg = (const float*)d_in[18];
  const float* lnfb = (const float*)d_in[19];
  const float* Wlm  = (const float*)d_in[20];
  float* out = (float*)d_out;

  char* w = (char*)d_ws;
  size_t off = 0;
  auto alloc = [&](size_t bytes) { void* p = w + off; off = (off + bytes + 255) & ~(size_t)255; return p; };
  float* h     = (float*)alloc((size_t)M_ * H_ * 4);
  float* ctxb  = (float*)alloc((size_t)M_ * H_ * 4);
  unsigned short* qkvb  = (unsigned short*)alloc((size_t)M_ * QS_ * 2);
  unsigned short* vtb   = (unsigned short*)alloc((size_t)B_ * NH_ * DH_ * S_ * 2);
  unsigned short* xbf   = (unsigned short*)alloc((size_t)M_ * H_ * 2);
  unsigned short* midbf = (unsigned short*)alloc((size_t)M_ * I_ * 2);
  unsigned short* wbuf  = (unsigned short*)alloc((size_t)V_ * H_ * 2);  // JIT bf16 weights
  float* bqkv  = (float*)alloc((size_t)L_ * QS_ * 4);

  bcat<<<dim3(L_ * QS_ / 256), 256, 0, stream>>>(bq, bk, bv, bqkv);
  embed_kernel<<<dim3(M_, H_ / 256), 256, 0, stream>>>(ids, tok, pos, h, xbf);

  for (int l = 0; l < L_; ++l) {
    // fused QKV
    qkvcat<<<dim3(3 * H_ * H_ / 1024), 256, 0, stream>>>(
        Wq + (size_t)l * H_ * H_, Wk + (size_t)l * H_ * H_, Wv + (size_t)l * H_ * H_, wbuf);
    gemm_bt<2><<<dim3(M_ / 128, QS_ / 128), 256, 0, stream>>>(
        xbf, wbuf, bqkv + (size_t)l * QS_, nullptr, qkvb, M_, QS_, H_);

    transpose_v_bf16<<<dim3(S_ / 32, DH_ / 32, B_ * NH_), dim3(32, 8), 0, stream>>>(
        qkvb + 2 * H_, vtb);
    flash_mfma<<<dim3(B_ * NH_ * S_ / 64), 256, 0, stream>>>(
        qkvb, qkvb + H_, vtb, mask, ctxb);

    add_ln<<<dim3(M_), 256, 0, stream>>>(h, ctxb, ln1g + l * H_, ln1b + l * H_, h, xbf);

    wcvt<<<dim3(I_ * H_ / 1024), 256, 0, stream>>>(Wi + (size_t)l * I_ * H_, wbuf);
    gemm_bt<1><<<dim3(M_ / 128, I_ / 128), 256, 0, stream>>>(
        xbf, wbuf, bi + l * I_, nullptr, midbf, M_, I_, H_);
    wcvt<<<dim3(H_ * I_ / 1024), 256, 0, stream>>>(Wo + (size_t)l * H_ * I_, wbuf);
    gemm_bt<0><<<dim3(M_ / 128, H_ / 128), 256, 0, stream>>>(
        midbf, wbuf, bo + l * H_, ctxb, nullptr, M_, H_, I_);

    add_ln<<<dim3(M_), 256, 0, stream>>>(h, ctxb, ln2g + l * H_, ln2b + l * H_, h, xbf);
  }

  add_ln<<<dim3(M_), 256, 0, stream>>>(h, nullptr, lnfg, lnfb, nullptr, xbf);
  wcvt<<<dim3(V_ * H_ / 1024), 256, 0, stream>>>(Wlm, wbuf);
  gemm_bt<0><<<dim3(M_ / 128, V_ / 128), 256, 0, stream>>>(
      xbf, wbuf, nullptr, out, nullptr, M_, V_, H_);
}